// Round 11
// baseline (180.228 us; speedup 1.0000x reference)
//
#include <hip/hip_runtime.h>

// FFF tree-routed feedforward: B=65536, nIn=nOut=1024, DEPTH=10, n_nodes=1023.
//
// Round-11 (isolated test of the route x-prefetch):
//  - route_kernel: R8 structure (levels 0..4 from 124KB LDS, levels 5..9
//    global) + software-pipelined x prefetch: next pair's x issued BEFORE the
//    current pair's 10-level dependent chain (~600cyc HBM latency hides under
//    ~4000cyc of routing).
//  - accum_kernel: byte-identical to R8's 2-sample form (passed twice).
//    R9/R10 post-mortem: the 4-sample blocking + readlane + 16 stream-store
//    combination is convicted of the correctness failures (mechanism unclear
//    from source; do not reintroduce).
//  - store_stream (sc0 sc1 nt): R7-proven, kills MALL write-allocate phantom.

#define FFF_DEPTH 10
#define N_IN 1024
#define N_OUT 1024
#define N_LEAF 512
#define LEAF_BASE 511
#define BIN_CAP 512
#define N_STAGE 31            // nodes in levels 0..4
#define ROUTE_THREADS 1024
#define ROUTE_BLOCKS 256

typedef float f32x4 __attribute__((ext_vector_type(4)));

template<int CTRL, int ROW_MASK>
__device__ __forceinline__ float dpp_add(float v) {
    int sh = __builtin_amdgcn_update_dpp(0, __builtin_bit_cast(int, v),
                                         CTRL, ROW_MASK, 0xf, true);
    return v + __builtin_bit_cast(float, sh);
}

// Full 64-lane sum, result broadcast via readlane(63) (wave-uniform).
__device__ __forceinline__ float wave_sum(float p) {
    p = dpp_add<0x111, 0xf>(p);
    p = dpp_add<0x112, 0xf>(p);
    p = dpp_add<0x114, 0xf>(p);
    p = dpp_add<0x118, 0xf>(p);
    p = dpp_add<0x142, 0xa>(p);
    p = dpp_add<0x143, 0xc>(p);
    return __builtin_bit_cast(float,
        __builtin_amdgcn_readlane(__builtin_bit_cast(int, p), 63));
}

// System-scope streaming store: bypasses L2 AND MALL allocate, so the store
// does not trigger a line fetch from HBM (R7-verified: killed ~360MB phantom).
__device__ __forceinline__ void store_stream(f32x4 v, f32x4* addr) {
    asm volatile("global_store_dwordx4 %0, %1, off sc0 sc1 nt"
                 :: "v"(addr), "v"(v) : "memory");
}

// One routing level for both of the wave's samples. Math identical across
// LDS/global sources (same op order) -> bitwise-stable lams.
#define ROUTE_LEVEL_BODY(dd, wa, wb)                                          \
    {                                                                         \
        f32x4 w0[4], w1v[4];                                                  \
        _Pragma("unroll")                                                     \
        for (int c = 0; c < 4; ++c) {                                         \
            w0[c] = (wa)[c * 64 + lane];                                      \
            w1v[c] = (wb)[c * 64 + lane];                                     \
        }                                                                     \
        float p0 = 0.f, p1 = 0.f, p2 = 0.f, p3 = 0.f;                         \
        float q0 = 0.f, q1 = 0.f, q2 = 0.f, q3 = 0.f;                         \
        _Pragma("unroll")                                                     \
        for (int c = 0; c < 4; ++c) {                                         \
            p0 += xv0[c][0] * w0[c][0];  q0 += xv1[c][0] * w1v[c][0];         \
            p1 += xv0[c][1] * w0[c][1];  q1 += xv1[c][1] * w1v[c][1];         \
            p2 += xv0[c][2] * w0[c][2];  q2 += xv1[c][2] * w1v[c][2];         \
            p3 += xv0[c][3] * w0[c][3];  q3 += xv1[c][3] * w1v[c][3];         \
        }                                                                     \
        const float lam0 = wave_sum((p0 + p1) + (p2 + p3));                   \
        const float lam1 = wave_sum((q0 + q1) + (q2 + q3));                   \
        const float pick = (lane < 16) ? lam0 : lam1;                         \
        myl = (sel == (dd)) ? pick : myl;                                     \
        n0 = n0 * 2 + 1 + (lam0 > 0.f ? 1 : 0);                               \
        n1 = n1 * 2 + 1 + (lam1 > 0.f ? 1 : 0);                               \
    }

// ---------------- Phase 1: routing (R8 + x prefetch) ----------------
__global__ __launch_bounds__(ROUTE_THREADS, 4) void route_kernel(
    const float* __restrict__ x,
    const float* __restrict__ w1s,
    float* __restrict__ lams16,     // [B][16], one 64B line per sample
    int* __restrict__ bins,         // [512][BIN_CAP]
    int* __restrict__ cnt,          // [512], pre-zeroed
    int B)
{
    extern __shared__ float w1_lds[];   // 31 rows x 1024 f32 = 124KB

    // Stage levels 0..4 (first 31 rows of w1s, contiguous) once per block.
    {
        f32x4* dst = reinterpret_cast<f32x4*>(w1_lds);
        const f32x4* src = reinterpret_cast<const f32x4*>(w1s);
        for (int i = threadIdx.x; i < N_STAGE * 256; i += ROUTE_THREADS)
            dst[i] = src[i];
    }
    __syncthreads();

    const int lane = threadIdx.x & 63;
    const int wslot = blockIdx.x * (ROUTE_THREADS / 64) + (threadIdx.x >> 6);
    const int wstride = gridDim.x * (ROUTE_THREADS / 64);
    const int npairs = B >> 1;
    const int sel = lane & 15;

    if (wslot >= npairs) return;

    // Prologue: load first pair's x.
    f32x4 xv0[4], xv1[4];
    {
        const f32x4* xa = reinterpret_cast<const f32x4*>(x + (size_t)(wslot * 2) * N_IN);
        const f32x4* xb = reinterpret_cast<const f32x4*>(x + (size_t)(wslot * 2 + 1) * N_IN);
        #pragma unroll
        for (int c = 0; c < 4; ++c) {
            xv0[c] = __builtin_nontemporal_load(&xa[c * 64 + lane]);
            xv1[c] = __builtin_nontemporal_load(&xb[c * 64 + lane]);
        }
    }

    for (int pr = wslot; pr < npairs; pr += wstride) {
        const int b0 = pr * 2, b1 = b0 + 1;

        // Prefetch next pair's x BEFORE the 10-level dependent chain.
        f32x4 xn0[4], xn1[4];
        const int nxt = (pr + wstride < npairs) ? pr + wstride : pr;
        {
            const f32x4* xa = reinterpret_cast<const f32x4*>(x + (size_t)(nxt * 2) * N_IN);
            const f32x4* xb = reinterpret_cast<const f32x4*>(x + (size_t)(nxt * 2 + 1) * N_IN);
            #pragma unroll
            for (int c = 0; c < 4; ++c) {
                xn0[c] = __builtin_nontemporal_load(&xa[c * 64 + lane]);
                xn1[c] = __builtin_nontemporal_load(&xb[c * 64 + lane]);
            }
        }

        float myl = 0.f;
        int n0 = 0, n1 = 0;

        // Levels 0..4: rows from LDS.
        #pragma unroll
        for (int d = 0; d < 5; ++d) {
            const f32x4* wa = reinterpret_cast<const f32x4*>(w1_lds + n0 * N_IN);
            const f32x4* wb = reinterpret_cast<const f32x4*>(w1_lds + n1 * N_IN);
            ROUTE_LEVEL_BODY(d, wa, wb)
        }
        // Levels 5..9: rows from global (L1/L2).
        #pragma unroll
        for (int d = 5; d < FFF_DEPTH; ++d) {
            const f32x4* wa = reinterpret_cast<const f32x4*>(w1s + (size_t)n0 * N_IN);
            const f32x4* wb = reinterpret_cast<const f32x4*>(w1s + (size_t)n1 * N_IN);
            ROUTE_LEVEL_BODY(d, wa, wb)
        }

        // One coalesced 128B store covers both samples' lam lines.
        if (lane < 32) lams16[(size_t)b0 * 16 + lane] = (sel < FFF_DEPTH) ? myl : 0.f;

        // Direct bin append (leaf = depth-9 node = parent of final index).
        if (lane == 0) {
            int l0 = ((n0 - 1) >> 1) - LEAF_BASE;
            int p = atomicAdd(&cnt[l0], 1);
            if (p < BIN_CAP) bins[l0 * BIN_CAP + p] = b0;
        }
        if (lane == 1) {
            int l1 = ((n1 - 1) >> 1) - LEAF_BASE;
            int p = atomicAdd(&cnt[l1], 1);
            if (p < BIN_CAP) bins[l1 * BIN_CAP + p] = b1;
        }

        // Rotate prefetched x into place.
        #pragma unroll
        for (int c = 0; c < 4; ++c) { xv0[c] = xn0[c]; xv1[c] = xn1[c]; }
    }
}

// ---------------- cnt zeroing (replaces hipMemsetAsync) ----------------
__global__ void zero_cnt_kernel(int* __restrict__ cnt) {
    cnt[threadIdx.x] = 0;
}

// ---------------- Phase 2: y accumulation (byte-identical to R8) ----------
__global__ __launch_bounds__(256, 4) void accum_kernel(
    const float* __restrict__ w2s,
    const float* __restrict__ lams16,
    const int* __restrict__ bins,
    const int* __restrict__ cnt,
    float* __restrict__ y)
{
    __shared__ float lds[FFF_DEPTH * N_OUT];   // 40KB: this leaf-path's w2 rows
    const int leaf = blockIdx.x >> 1;          // 2 blocks per leaf
    const int half = blockIdx.x & 1;

    int nodes[FFF_DEPTH];
    int n = LEAF_BASE + leaf;
    #pragma unroll
    for (int d = FFF_DEPTH - 1; d >= 0; --d) { nodes[d] = n; n = (n - 1) >> 1; }

    const int tid = threadIdx.x;
    f32x4* lds4 = reinterpret_cast<f32x4*>(lds);
    #pragma unroll
    for (int d = 0; d < FFF_DEPTH; ++d) {
        const f32x4* src = reinterpret_cast<const f32x4*>(w2s + (size_t)nodes[d] * N_OUT);
        lds4[d * 256 + tid] = src[tid];        // 256 thr x float4 = one 4KB row
    }
    __syncthreads();

    int nsamp = cnt[leaf];
    if (nsamp > BIN_CAP) nsamp = BIN_CAP;      // safety (never expected)
    const int nh = (nsamp + 1) >> 1;
    const int rs = half ? nh : 0;
    const int re = half ? nsamp : nh;

    const int lane = tid & 63, wv = tid >> 6;
    const int* mybin = bins + leaf * BIN_CAP;

    int p = rs + wv;

    // Main loop: 2 samples/iter; each LDS w-row read feeds both accumulators.
    for (; p + 4 < re; p += 8) {
        const int b0 = __builtin_amdgcn_readfirstlane(mybin[p]);
        const int b1 = __builtin_amdgcn_readfirstlane(mybin[p + 4]);
        const float lv0 = lams16[(size_t)b0 * 16 + (lane & 15)];
        const float lv1 = lams16[(size_t)b1 * 16 + (lane & 15)];

        f32x4 a0[4], a1[4];
        #pragma unroll
        for (int c = 0; c < 4; ++c) { a0[c] = (f32x4)0.f; a1[c] = (f32x4)0.f; }
        #pragma unroll
        for (int d = 0; d < FFF_DEPTH; ++d) {      // d-ascending, same as ref
            const float s0 = __builtin_bit_cast(float,
                __builtin_amdgcn_readlane(__builtin_bit_cast(int, lv0), d));
            const float s1 = __builtin_bit_cast(float,
                __builtin_amdgcn_readlane(__builtin_bit_cast(int, lv1), d));
            #pragma unroll
            for (int c = 0; c < 4; ++c) {
                const f32x4 w = lds4[d * 256 + c * 64 + lane];
                a0[c] += s0 * w;
                a1[c] += s1 * w;
            }
        }
        f32x4* y0 = reinterpret_cast<f32x4*>(y + (size_t)b0 * N_OUT);
        f32x4* y1 = reinterpret_cast<f32x4*>(y + (size_t)b1 * N_OUT);
        #pragma unroll
        for (int c = 0; c < 4; ++c) {
            store_stream(a0[c], &y0[c * 64 + lane]);
            store_stream(a1[c], &y1[c * 64 + lane]);
        }
    }

    // Tail: one sample at a time.
    for (; p < re; p += 4) {
        const int b = __builtin_amdgcn_readfirstlane(mybin[p]);
        const float lv = lams16[(size_t)b * 16 + (lane & 15)];
        f32x4 acc[4];
        #pragma unroll
        for (int c = 0; c < 4; ++c) acc[c] = (f32x4)0.f;
        #pragma unroll
        for (int d = 0; d < FFF_DEPTH; ++d) {
            const float s = __builtin_bit_cast(float,
                __builtin_amdgcn_readlane(__builtin_bit_cast(int, lv), d));
            #pragma unroll
            for (int c = 0; c < 4; ++c) acc[c] += s * lds4[d * 256 + c * 64 + lane];
        }
        f32x4* y4 = reinterpret_cast<f32x4*>(y + (size_t)b * N_OUT);
        #pragma unroll
        for (int c = 0; c < 4; ++c) store_stream(acc[c], &y4[c * 64 + lane]);
    }
}

// ---------------- Fallback (round-3 proven kernel) ----------------
__global__ __launch_bounds__(256, 4) void fff_mono_kernel(
    const float* __restrict__ x, const float* __restrict__ w1s,
    const float* __restrict__ w2s, float* __restrict__ y, int B)
{
    const int lane = threadIdx.x & 63;
    const int b = blockIdx.x * 4 + (threadIdx.x >> 6);
    if (b >= B) return;
    const f32x4* x4 = reinterpret_cast<const f32x4*>(x + (size_t)b * N_IN);
    f32x4 xv[4], acc[4];
    #pragma unroll
    for (int c = 0; c < 4; ++c) { xv[c] = __builtin_nontemporal_load(&x4[c*64+lane]); acc[c] = (f32x4)0.f; }
    int node = 0;
    #pragma unroll
    for (int d = 0; d < FFF_DEPTH; ++d) {
        const f32x4* w1 = reinterpret_cast<const f32x4*>(w1s + (size_t)node * N_IN);
        const f32x4* w2 = reinterpret_cast<const f32x4*>(w2s + (size_t)node * N_OUT);
        f32x4 w[4], v[4];
        #pragma unroll
        for (int c = 0; c < 4; ++c) { w[c] = w1[c*64+lane]; v[c] = w2[c*64+lane]; }
        float p0=0,p1=0,p2=0,p3=0;
        #pragma unroll
        for (int c = 0; c < 4; ++c) {
            p0 += xv[c][0]*w[c][0]; p1 += xv[c][1]*w[c][1];
            p2 += xv[c][2]*w[c][2]; p3 += xv[c][3]*w[c][3];
        }
        float lam = wave_sum((p0+p1)+(p2+p3));
        #pragma unroll
        for (int c = 0; c < 4; ++c) acc[c] += lam * v[c];
        node = node * 2 + 1 + (lam > 0.f ? 1 : 0);
    }
    f32x4* y4 = reinterpret_cast<f32x4*>(y + (size_t)b * N_OUT);
    #pragma unroll
    for (int c = 0; c < 4; ++c) store_stream(acc[c], &y4[c*64+lane]);
}

extern "C" void kernel_launch(void* const* d_in, const int* in_sizes, int n_in,
                              void* d_out, int out_size, void* d_ws, size_t ws_size,
                              hipStream_t stream) {
    const float* x   = (const float*)d_in[0];
    const float* w1s = (const float*)d_in[1];
    const float* w2s = (const float*)d_in[2];
    float* y = (float*)d_out;
    const int B = in_sizes[0] / N_IN;   // 65536

    float* lams16 = (float*)d_ws;
    int*   bins   = (int*)(lams16 + (size_t)B * 16);
    int*   cnt    = bins + (size_t)N_LEAF * BIN_CAP;
    const size_t need = ((size_t)B * 16 + (size_t)N_LEAF * BIN_CAP + N_LEAF) * 4;

    if (ws_size < need) {   // fallback: monolithic proven path
        fff_mono_kernel<<<(B + 3) / 4, 256, 0, stream>>>(x, w1s, w2s, y, B);
        return;
    }

    zero_cnt_kernel<<<1, N_LEAF, 0, stream>>>(cnt);
    route_kernel<<<ROUTE_BLOCKS, ROUTE_THREADS, N_STAGE * N_IN * sizeof(float), stream>>>(
        x, w1s, lams16, bins, cnt, B);
    accum_kernel<<<2 * N_LEAF, 256, 0, stream>>>(w2s, lams16, bins, cnt, y);
}

// Round 12
// 168.393 us; speedup vs baseline: 1.0703x; 1.0703x over previous
//
#include <hip/hip_runtime.h>

// FFF tree-routed feedforward: B=65536, nIn=nOut=1024, DEPTH=10, n_nodes=1023.
//
// Round-12:
//  - route_kernel: byte-identical to R8 (best measured; R11's x-prefetch was
//    correctness-safe but -6us from VGPR pressure at 1 block/CU -> dropped).
//  - accum_kernel: R8's proven 2-sample inner loop, but 4 blocks per leaf
//    (2048 blocks) instead of 2: the old grid was exactly 4 blocks/CU with
//    zero refill slack, so CUs holding fat leaves (Binomial max ~170 vs mean
//    128) straggled. Quartering per-block work + 8 slots/CU shrinks the tail.
//  - R9/R10 lesson (banked): the 4-sample accum blocking + readlane + 16
//    stream-store combo silently corrupts output. Do not reintroduce.

#define FFF_DEPTH 10
#define N_IN 1024
#define N_OUT 1024
#define N_LEAF 512
#define LEAF_BASE 511
#define BIN_CAP 512
#define N_STAGE 31            // nodes in levels 0..4
#define ROUTE_THREADS 1024
#define ROUTE_BLOCKS 256
#define BLOCKS_PER_LEAF 4

typedef float f32x4 __attribute__((ext_vector_type(4)));

template<int CTRL, int ROW_MASK>
__device__ __forceinline__ float dpp_add(float v) {
    int sh = __builtin_amdgcn_update_dpp(0, __builtin_bit_cast(int, v),
                                         CTRL, ROW_MASK, 0xf, true);
    return v + __builtin_bit_cast(float, sh);
}

// Full 64-lane sum, result broadcast via readlane(63) (wave-uniform).
__device__ __forceinline__ float wave_sum(float p) {
    p = dpp_add<0x111, 0xf>(p);
    p = dpp_add<0x112, 0xf>(p);
    p = dpp_add<0x114, 0xf>(p);
    p = dpp_add<0x118, 0xf>(p);
    p = dpp_add<0x142, 0xa>(p);
    p = dpp_add<0x143, 0xc>(p);
    return __builtin_bit_cast(float,
        __builtin_amdgcn_readlane(__builtin_bit_cast(int, p), 63));
}

// System-scope streaming store: bypasses L2 AND MALL allocate, so the store
// does not trigger a line fetch from HBM (R7-verified: killed ~360MB phantom).
__device__ __forceinline__ void store_stream(f32x4 v, f32x4* addr) {
    asm volatile("global_store_dwordx4 %0, %1, off sc0 sc1 nt"
                 :: "v"(addr), "v"(v) : "memory");
}

// One routing level for both of the wave's samples. Math identical across
// LDS/global sources (same op order) -> bitwise-stable lams.
#define ROUTE_LEVEL_BODY(dd, wa, wb)                                          \
    {                                                                         \
        f32x4 w0[4], w1v[4];                                                  \
        _Pragma("unroll")                                                     \
        for (int c = 0; c < 4; ++c) {                                         \
            w0[c] = (wa)[c * 64 + lane];                                      \
            w1v[c] = (wb)[c * 64 + lane];                                     \
        }                                                                     \
        float p0 = 0.f, p1 = 0.f, p2 = 0.f, p3 = 0.f;                         \
        float q0 = 0.f, q1 = 0.f, q2 = 0.f, q3 = 0.f;                         \
        _Pragma("unroll")                                                     \
        for (int c = 0; c < 4; ++c) {                                         \
            p0 += xv0[c][0] * w0[c][0];  q0 += xv1[c][0] * w1v[c][0];         \
            p1 += xv0[c][1] * w0[c][1];  q1 += xv1[c][1] * w1v[c][1];         \
            p2 += xv0[c][2] * w0[c][2];  q2 += xv1[c][2] * w1v[c][2];         \
            p3 += xv0[c][3] * w0[c][3];  q3 += xv1[c][3] * w1v[c][3];         \
        }                                                                     \
        const float lam0 = wave_sum((p0 + p1) + (p2 + p3));                   \
        const float lam1 = wave_sum((q0 + q1) + (q2 + q3));                   \
        const float pick = (lane < 16) ? lam0 : lam1;                         \
        myl = (sel == (dd)) ? pick : myl;                                     \
        n0 = n0 * 2 + 1 + (lam0 > 0.f ? 1 : 0);                               \
        n1 = n1 * 2 + 1 + (lam1 > 0.f ? 1 : 0);                               \
    }

// ---------------- Phase 1: routing (byte-identical to R8) ----------------
__global__ __launch_bounds__(ROUTE_THREADS, 4) void route_kernel(
    const float* __restrict__ x,
    const float* __restrict__ w1s,
    float* __restrict__ lams16,     // [B][16], one 64B line per sample
    int* __restrict__ bins,         // [512][BIN_CAP]
    int* __restrict__ cnt,          // [512], pre-zeroed
    int B)
{
    extern __shared__ float w1_lds[];   // 31 rows x 1024 f32 = 124KB

    // Stage levels 0..4 (first 31 rows of w1s, contiguous) once per block.
    {
        f32x4* dst = reinterpret_cast<f32x4*>(w1_lds);
        const f32x4* src = reinterpret_cast<const f32x4*>(w1s);
        for (int i = threadIdx.x; i < N_STAGE * 256; i += ROUTE_THREADS)
            dst[i] = src[i];
    }
    __syncthreads();

    const int lane = threadIdx.x & 63;
    const int wslot = blockIdx.x * (ROUTE_THREADS / 64) + (threadIdx.x >> 6);
    const int wstride = gridDim.x * (ROUTE_THREADS / 64);
    const int npairs = B >> 1;
    const int sel = lane & 15;

    for (int pr = wslot; pr < npairs; pr += wstride) {
        const int b0 = pr * 2, b1 = b0 + 1;

        const f32x4* xa = reinterpret_cast<const f32x4*>(x + (size_t)b0 * N_IN);
        const f32x4* xb = reinterpret_cast<const f32x4*>(x + (size_t)b1 * N_IN);
        f32x4 xv0[4], xv1[4];
        #pragma unroll
        for (int c = 0; c < 4; ++c) {
            xv0[c] = __builtin_nontemporal_load(&xa[c * 64 + lane]);
            xv1[c] = __builtin_nontemporal_load(&xb[c * 64 + lane]);
        }

        float myl = 0.f;
        int n0 = 0, n1 = 0;

        // Levels 0..4: rows from LDS.
        #pragma unroll
        for (int d = 0; d < 5; ++d) {
            const f32x4* wa = reinterpret_cast<const f32x4*>(w1_lds + n0 * N_IN);
            const f32x4* wb = reinterpret_cast<const f32x4*>(w1_lds + n1 * N_IN);
            ROUTE_LEVEL_BODY(d, wa, wb)
        }
        // Levels 5..9: rows from global (L1/L2).
        #pragma unroll
        for (int d = 5; d < FFF_DEPTH; ++d) {
            const f32x4* wa = reinterpret_cast<const f32x4*>(w1s + (size_t)n0 * N_IN);
            const f32x4* wb = reinterpret_cast<const f32x4*>(w1s + (size_t)n1 * N_IN);
            ROUTE_LEVEL_BODY(d, wa, wb)
        }

        // One coalesced 128B store covers both samples' lam lines.
        if (lane < 32) lams16[(size_t)b0 * 16 + lane] = (sel < FFF_DEPTH) ? myl : 0.f;

        // Direct bin append (leaf = depth-9 node = parent of final index).
        if (lane == 0) {
            int l0 = ((n0 - 1) >> 1) - LEAF_BASE;
            int p = atomicAdd(&cnt[l0], 1);
            if (p < BIN_CAP) bins[l0 * BIN_CAP + p] = b0;
        }
        if (lane == 1) {
            int l1 = ((n1 - 1) >> 1) - LEAF_BASE;
            int p = atomicAdd(&cnt[l1], 1);
            if (p < BIN_CAP) bins[l1 * BIN_CAP + p] = b1;
        }
    }
}

// ---------------- cnt zeroing (replaces hipMemsetAsync) ----------------
__global__ void zero_cnt_kernel(int* __restrict__ cnt) {
    cnt[threadIdx.x] = 0;
}

// ---------------- Phase 2: y accumulation (R8 loop, 4 blocks/leaf) --------
__global__ __launch_bounds__(256, 4) void accum_kernel(
    const float* __restrict__ w2s,
    const float* __restrict__ lams16,
    const int* __restrict__ bins,
    const int* __restrict__ cnt,
    float* __restrict__ y)
{
    __shared__ float lds[FFF_DEPTH * N_OUT];   // 40KB: this leaf-path's w2 rows
    const int leaf = blockIdx.x >> 2;          // 4 blocks per leaf
    const int quarter = blockIdx.x & 3;

    int nodes[FFF_DEPTH];
    int n = LEAF_BASE + leaf;
    #pragma unroll
    for (int d = FFF_DEPTH - 1; d >= 0; --d) { nodes[d] = n; n = (n - 1) >> 1; }

    const int tid = threadIdx.x;
    f32x4* lds4 = reinterpret_cast<f32x4*>(lds);
    #pragma unroll
    for (int d = 0; d < FFF_DEPTH; ++d) {
        const f32x4* src = reinterpret_cast<const f32x4*>(w2s + (size_t)nodes[d] * N_OUT);
        lds4[d * 256 + tid] = src[tid];        // 256 thr x float4 = one 4KB row
    }
    __syncthreads();

    int nsamp = cnt[leaf];
    if (nsamp > BIN_CAP) nsamp = BIN_CAP;      // safety (never expected)
    const int nq = (nsamp + BLOCKS_PER_LEAF - 1) / BLOCKS_PER_LEAF;
    const int rs = quarter * nq;
    int re = rs + nq;
    if (re > nsamp) re = nsamp;

    const int lane = tid & 63, wv = tid >> 6;
    const int* mybin = bins + leaf * BIN_CAP;

    int p = rs + wv;

    // Main loop: 2 samples/iter; each LDS w-row read feeds both accumulators.
    for (; p + 4 < re; p += 8) {
        const int b0 = __builtin_amdgcn_readfirstlane(mybin[p]);
        const int b1 = __builtin_amdgcn_readfirstlane(mybin[p + 4]);
        const float lv0 = lams16[(size_t)b0 * 16 + (lane & 15)];
        const float lv1 = lams16[(size_t)b1 * 16 + (lane & 15)];

        f32x4 a0[4], a1[4];
        #pragma unroll
        for (int c = 0; c < 4; ++c) { a0[c] = (f32x4)0.f; a1[c] = (f32x4)0.f; }
        #pragma unroll
        for (int d = 0; d < FFF_DEPTH; ++d) {      // d-ascending, same as ref
            const float s0 = __builtin_bit_cast(float,
                __builtin_amdgcn_readlane(__builtin_bit_cast(int, lv0), d));
            const float s1 = __builtin_bit_cast(float,
                __builtin_amdgcn_readlane(__builtin_bit_cast(int, lv1), d));
            #pragma unroll
            for (int c = 0; c < 4; ++c) {
                const f32x4 w = lds4[d * 256 + c * 64 + lane];
                a0[c] += s0 * w;
                a1[c] += s1 * w;
            }
        }
        f32x4* y0 = reinterpret_cast<f32x4*>(y + (size_t)b0 * N_OUT);
        f32x4* y1 = reinterpret_cast<f32x4*>(y + (size_t)b1 * N_OUT);
        #pragma unroll
        for (int c = 0; c < 4; ++c) {
            store_stream(a0[c], &y0[c * 64 + lane]);
            store_stream(a1[c], &y1[c * 64 + lane]);
        }
    }

    // Tail: one sample at a time.
    for (; p < re; p += 4) {
        const int b = __builtin_amdgcn_readfirstlane(mybin[p]);
        const float lv = lams16[(size_t)b * 16 + (lane & 15)];
        f32x4 acc[4];
        #pragma unroll
        for (int c = 0; c < 4; ++c) acc[c] = (f32x4)0.f;
        #pragma unroll
        for (int d = 0; d < FFF_DEPTH; ++d) {
            const float s = __builtin_bit_cast(float,
                __builtin_amdgcn_readlane(__builtin_bit_cast(int, lv), d));
            #pragma unroll
            for (int c = 0; c < 4; ++c) acc[c] += s * lds4[d * 256 + c * 64 + lane];
        }
        f32x4* y4 = reinterpret_cast<f32x4*>(y + (size_t)b * N_OUT);
        #pragma unroll
        for (int c = 0; c < 4; ++c) store_stream(acc[c], &y4[c * 64 + lane]);
    }
}

// ---------------- Fallback (round-3 proven kernel) ----------------
__global__ __launch_bounds__(256, 4) void fff_mono_kernel(
    const float* __restrict__ x, const float* __restrict__ w1s,
    const float* __restrict__ w2s, float* __restrict__ y, int B)
{
    const int lane = threadIdx.x & 63;
    const int b = blockIdx.x * 4 + (threadIdx.x >> 6);
    if (b >= B) return;
    const f32x4* x4 = reinterpret_cast<const f32x4*>(x + (size_t)b * N_IN);
    f32x4 xv[4], acc[4];
    #pragma unroll
    for (int c = 0; c < 4; ++c) { xv[c] = __builtin_nontemporal_load(&x4[c*64+lane]); acc[c] = (f32x4)0.f; }
    int node = 0;
    #pragma unroll
    for (int d = 0; d < FFF_DEPTH; ++d) {
        const f32x4* w1 = reinterpret_cast<const f32x4*>(w1s + (size_t)node * N_IN);
        const f32x4* w2 = reinterpret_cast<const f32x4*>(w2s + (size_t)node * N_OUT);
        f32x4 w[4], v[4];
        #pragma unroll
        for (int c = 0; c < 4; ++c) { w[c] = w1[c*64+lane]; v[c] = w2[c*64+lane]; }
        float p0=0,p1=0,p2=0,p3=0;
        #pragma unroll
        for (int c = 0; c < 4; ++c) {
            p0 += xv[c][0]*w[c][0]; p1 += xv[c][1]*w[c][1];
            p2 += xv[c][2]*w[c][2]; p3 += xv[c][3]*w[c][3];
        }
        float lam = wave_sum((p0+p1)+(p2+p3));
        #pragma unroll
        for (int c = 0; c < 4; ++c) acc[c] += lam * v[c];
        node = node * 2 + 1 + (lam > 0.f ? 1 : 0);
    }
    f32x4* y4 = reinterpret_cast<f32x4*>(y + (size_t)b * N_OUT);
    #pragma unroll
    for (int c = 0; c < 4; ++c) store_stream(acc[c], &y4[c*64+lane]);
}

extern "C" void kernel_launch(void* const* d_in, const int* in_sizes, int n_in,
                              void* d_out, int out_size, void* d_ws, size_t ws_size,
                              hipStream_t stream) {
    const float* x   = (const float*)d_in[0];
    const float* w1s = (const float*)d_in[1];
    const float* w2s = (const float*)d_in[2];
    float* y = (float*)d_out;
    const int B = in_sizes[0] / N_IN;   // 65536

    float* lams16 = (float*)d_ws;
    int*   bins   = (int*)(lams16 + (size_t)B * 16);
    int*   cnt    = bins + (size_t)N_LEAF * BIN_CAP;
    const size_t need = ((size_t)B * 16 + (size_t)N_LEAF * BIN_CAP + N_LEAF) * 4;

    if (ws_size < need) {   // fallback: monolithic proven path
        fff_mono_kernel<<<(B + 3) / 4, 256, 0, stream>>>(x, w1s, w2s, y, B);
        return;
    }

    zero_cnt_kernel<<<1, N_LEAF, 0, stream>>>(cnt);
    route_kernel<<<ROUTE_BLOCKS, ROUTE_THREADS, N_STAGE * N_IN * sizeof(float), stream>>>(
        x, w1s, lams16, bins, cnt, B);
    accum_kernel<<<BLOCKS_PER_LEAF * N_LEAF, 256, 0, stream>>>(w2s, lams16, bins, cnt, y);
}

// Round 13
// 164.577 us; speedup vs baseline: 1.0951x; 1.0232x over previous
//
#include <hip/hip_runtime.h>

// FFF tree-routed feedforward: B=65536, nIn=nOut=1024, DEPTH=10, n_nodes=1023.
//
// Round-13 (single change from R12):
//  - accum_kernel: 8 blocks per leaf (4096 blocks, 16 slots/CU). R12's move
//    2->4 blocks/leaf gained 6us by shrinking the straggler tail; accum is
//    still ~20us above its 262MB-write floor (~38us at the measured ~6.9TB/s
//    streaming-store ceiling), and per-block staging (0.3us) stays 10:1
//    amortized at ~16 samples/block.
//  - route_kernel: byte-identical to R8/R12. (Two-pass subtree-LDS split was
//    modeled: needs a second 268MB x read -> no net gain. 4-sample ILP and
//    smaller-stage/2-block variants exceed the 128-VGPR cap -> R11-style
//    regression. Route is at its vector-L1-return wall.)
//  - Banked lessons: sc0 sc1 nt streaming stores (R7, kills MALL
//    write-allocate phantom); 4-sample accum blocking combo corrupts (R9/R10).

#define FFF_DEPTH 10
#define N_IN 1024
#define N_OUT 1024
#define N_LEAF 512
#define LEAF_BASE 511
#define BIN_CAP 512
#define N_STAGE 31            // nodes in levels 0..4
#define ROUTE_THREADS 1024
#define ROUTE_BLOCKS 256
#define BLOCKS_PER_LEAF 8

typedef float f32x4 __attribute__((ext_vector_type(4)));

template<int CTRL, int ROW_MASK>
__device__ __forceinline__ float dpp_add(float v) {
    int sh = __builtin_amdgcn_update_dpp(0, __builtin_bit_cast(int, v),
                                         CTRL, ROW_MASK, 0xf, true);
    return v + __builtin_bit_cast(float, sh);
}

// Full 64-lane sum, result broadcast via readlane(63) (wave-uniform).
__device__ __forceinline__ float wave_sum(float p) {
    p = dpp_add<0x111, 0xf>(p);
    p = dpp_add<0x112, 0xf>(p);
    p = dpp_add<0x114, 0xf>(p);
    p = dpp_add<0x118, 0xf>(p);
    p = dpp_add<0x142, 0xa>(p);
    p = dpp_add<0x143, 0xc>(p);
    return __builtin_bit_cast(float,
        __builtin_amdgcn_readlane(__builtin_bit_cast(int, p), 63));
}

// System-scope streaming store: bypasses L2 AND MALL allocate, so the store
// does not trigger a line fetch from HBM (R7-verified: killed ~360MB phantom).
__device__ __forceinline__ void store_stream(f32x4 v, f32x4* addr) {
    asm volatile("global_store_dwordx4 %0, %1, off sc0 sc1 nt"
                 :: "v"(addr), "v"(v) : "memory");
}

// One routing level for both of the wave's samples. Math identical across
// LDS/global sources (same op order) -> bitwise-stable lams.
#define ROUTE_LEVEL_BODY(dd, wa, wb)                                          \
    {                                                                         \
        f32x4 w0[4], w1v[4];                                                  \
        _Pragma("unroll")                                                     \
        for (int c = 0; c < 4; ++c) {                                         \
            w0[c] = (wa)[c * 64 + lane];                                      \
            w1v[c] = (wb)[c * 64 + lane];                                     \
        }                                                                     \
        float p0 = 0.f, p1 = 0.f, p2 = 0.f, p3 = 0.f;                         \
        float q0 = 0.f, q1 = 0.f, q2 = 0.f, q3 = 0.f;                         \
        _Pragma("unroll")                                                     \
        for (int c = 0; c < 4; ++c) {                                         \
            p0 += xv0[c][0] * w0[c][0];  q0 += xv1[c][0] * w1v[c][0];         \
            p1 += xv0[c][1] * w0[c][1];  q1 += xv1[c][1] * w1v[c][1];         \
            p2 += xv0[c][2] * w0[c][2];  q2 += xv1[c][2] * w1v[c][2];         \
            p3 += xv0[c][3] * w0[c][3];  q3 += xv1[c][3] * w1v[c][3];         \
        }                                                                     \
        const float lam0 = wave_sum((p0 + p1) + (p2 + p3));                   \
        const float lam1 = wave_sum((q0 + q1) + (q2 + q3));                   \
        const float pick = (lane < 16) ? lam0 : lam1;                         \
        myl = (sel == (dd)) ? pick : myl;                                     \
        n0 = n0 * 2 + 1 + (lam0 > 0.f ? 1 : 0);                               \
        n1 = n1 * 2 + 1 + (lam1 > 0.f ? 1 : 0);                               \
    }

// ---------------- Phase 1: routing (byte-identical to R8/R12) -------------
__global__ __launch_bounds__(ROUTE_THREADS, 4) void route_kernel(
    const float* __restrict__ x,
    const float* __restrict__ w1s,
    float* __restrict__ lams16,     // [B][16], one 64B line per sample
    int* __restrict__ bins,         // [512][BIN_CAP]
    int* __restrict__ cnt,          // [512], pre-zeroed
    int B)
{
    extern __shared__ float w1_lds[];   // 31 rows x 1024 f32 = 124KB

    // Stage levels 0..4 (first 31 rows of w1s, contiguous) once per block.
    {
        f32x4* dst = reinterpret_cast<f32x4*>(w1_lds);
        const f32x4* src = reinterpret_cast<const f32x4*>(w1s);
        for (int i = threadIdx.x; i < N_STAGE * 256; i += ROUTE_THREADS)
            dst[i] = src[i];
    }
    __syncthreads();

    const int lane = threadIdx.x & 63;
    const int wslot = blockIdx.x * (ROUTE_THREADS / 64) + (threadIdx.x >> 6);
    const int wstride = gridDim.x * (ROUTE_THREADS / 64);
    const int npairs = B >> 1;
    const int sel = lane & 15;

    for (int pr = wslot; pr < npairs; pr += wstride) {
        const int b0 = pr * 2, b1 = b0 + 1;

        const f32x4* xa = reinterpret_cast<const f32x4*>(x + (size_t)b0 * N_IN);
        const f32x4* xb = reinterpret_cast<const f32x4*>(x + (size_t)b1 * N_IN);
        f32x4 xv0[4], xv1[4];
        #pragma unroll
        for (int c = 0; c < 4; ++c) {
            xv0[c] = __builtin_nontemporal_load(&xa[c * 64 + lane]);
            xv1[c] = __builtin_nontemporal_load(&xb[c * 64 + lane]);
        }

        float myl = 0.f;
        int n0 = 0, n1 = 0;

        // Levels 0..4: rows from LDS.
        #pragma unroll
        for (int d = 0; d < 5; ++d) {
            const f32x4* wa = reinterpret_cast<const f32x4*>(w1_lds + n0 * N_IN);
            const f32x4* wb = reinterpret_cast<const f32x4*>(w1_lds + n1 * N_IN);
            ROUTE_LEVEL_BODY(d, wa, wb)
        }
        // Levels 5..9: rows from global (L1/L2).
        #pragma unroll
        for (int d = 5; d < FFF_DEPTH; ++d) {
            const f32x4* wa = reinterpret_cast<const f32x4*>(w1s + (size_t)n0 * N_IN);
            const f32x4* wb = reinterpret_cast<const f32x4*>(w1s + (size_t)n1 * N_IN);
            ROUTE_LEVEL_BODY(d, wa, wb)
        }

        // One coalesced 128B store covers both samples' lam lines.
        if (lane < 32) lams16[(size_t)b0 * 16 + lane] = (sel < FFF_DEPTH) ? myl : 0.f;

        // Direct bin append (leaf = depth-9 node = parent of final index).
        if (lane == 0) {
            int l0 = ((n0 - 1) >> 1) - LEAF_BASE;
            int p = atomicAdd(&cnt[l0], 1);
            if (p < BIN_CAP) bins[l0 * BIN_CAP + p] = b0;
        }
        if (lane == 1) {
            int l1 = ((n1 - 1) >> 1) - LEAF_BASE;
            int p = atomicAdd(&cnt[l1], 1);
            if (p < BIN_CAP) bins[l1 * BIN_CAP + p] = b1;
        }
    }
}

// ---------------- cnt zeroing (replaces hipMemsetAsync) ----------------
__global__ void zero_cnt_kernel(int* __restrict__ cnt) {
    cnt[threadIdx.x] = 0;
}

// ---------------- Phase 2: y accumulation (R8 loop, 8 blocks/leaf) --------
__global__ __launch_bounds__(256, 4) void accum_kernel(
    const float* __restrict__ w2s,
    const float* __restrict__ lams16,
    const int* __restrict__ bins,
    const int* __restrict__ cnt,
    float* __restrict__ y)
{
    __shared__ float lds[FFF_DEPTH * N_OUT];   // 40KB: this leaf-path's w2 rows
    const int leaf = blockIdx.x >> 3;          // 8 blocks per leaf
    const int part = blockIdx.x & 7;

    int nodes[FFF_DEPTH];
    int n = LEAF_BASE + leaf;
    #pragma unroll
    for (int d = FFF_DEPTH - 1; d >= 0; --d) { nodes[d] = n; n = (n - 1) >> 1; }

    const int tid = threadIdx.x;
    f32x4* lds4 = reinterpret_cast<f32x4*>(lds);
    #pragma unroll
    for (int d = 0; d < FFF_DEPTH; ++d) {
        const f32x4* src = reinterpret_cast<const f32x4*>(w2s + (size_t)nodes[d] * N_OUT);
        lds4[d * 256 + tid] = src[tid];        // 256 thr x float4 = one 4KB row
    }
    __syncthreads();

    int nsamp = cnt[leaf];
    if (nsamp > BIN_CAP) nsamp = BIN_CAP;      // safety (never expected)
    const int nq = (nsamp + BLOCKS_PER_LEAF - 1) / BLOCKS_PER_LEAF;
    const int rs = part * nq;
    int re = rs + nq;
    if (re > nsamp) re = nsamp;

    const int lane = tid & 63, wv = tid >> 6;
    const int* mybin = bins + leaf * BIN_CAP;

    int p = rs + wv;

    // Main loop: 2 samples/iter; each LDS w-row read feeds both accumulators.
    for (; p + 4 < re; p += 8) {
        const int b0 = __builtin_amdgcn_readfirstlane(mybin[p]);
        const int b1 = __builtin_amdgcn_readfirstlane(mybin[p + 4]);
        const float lv0 = lams16[(size_t)b0 * 16 + (lane & 15)];
        const float lv1 = lams16[(size_t)b1 * 16 + (lane & 15)];

        f32x4 a0[4], a1[4];
        #pragma unroll
        for (int c = 0; c < 4; ++c) { a0[c] = (f32x4)0.f; a1[c] = (f32x4)0.f; }
        #pragma unroll
        for (int d = 0; d < FFF_DEPTH; ++d) {      // d-ascending, same as ref
            const float s0 = __builtin_bit_cast(float,
                __builtin_amdgcn_readlane(__builtin_bit_cast(int, lv0), d));
            const float s1 = __builtin_bit_cast(float,
                __builtin_amdgcn_readlane(__builtin_bit_cast(int, lv1), d));
            #pragma unroll
            for (int c = 0; c < 4; ++c) {
                const f32x4 w = lds4[d * 256 + c * 64 + lane];
                a0[c] += s0 * w;
                a1[c] += s1 * w;
            }
        }
        f32x4* y0 = reinterpret_cast<f32x4*>(y + (size_t)b0 * N_OUT);
        f32x4* y1 = reinterpret_cast<f32x4*>(y + (size_t)b1 * N_OUT);
        #pragma unroll
        for (int c = 0; c < 4; ++c) {
            store_stream(a0[c], &y0[c * 64 + lane]);
            store_stream(a1[c], &y1[c * 64 + lane]);
        }
    }

    // Tail: one sample at a time.
    for (; p < re; p += 4) {
        const int b = __builtin_amdgcn_readfirstlane(mybin[p]);
        const float lv = lams16[(size_t)b * 16 + (lane & 15)];
        f32x4 acc[4];
        #pragma unroll
        for (int c = 0; c < 4; ++c) acc[c] = (f32x4)0.f;
        #pragma unroll
        for (int d = 0; d < FFF_DEPTH; ++d) {
            const float s = __builtin_bit_cast(float,
                __builtin_amdgcn_readlane(__builtin_bit_cast(int, lv), d));
            #pragma unroll
            for (int c = 0; c < 4; ++c) acc[c] += s * lds4[d * 256 + c * 64 + lane];
        }
        f32x4* y4 = reinterpret_cast<f32x4*>(y + (size_t)b * N_OUT);
        #pragma unroll
        for (int c = 0; c < 4; ++c) store_stream(acc[c], &y4[c * 64 + lane]);
    }
}

// ---------------- Fallback (round-3 proven kernel) ----------------
__global__ __launch_bounds__(256, 4) void fff_mono_kernel(
    const float* __restrict__ x, const float* __restrict__ w1s,
    const float* __restrict__ w2s, float* __restrict__ y, int B)
{
    const int lane = threadIdx.x & 63;
    const int b = blockIdx.x * 4 + (threadIdx.x >> 6);
    if (b >= B) return;
    const f32x4* x4 = reinterpret_cast<const f32x4*>(x + (size_t)b * N_IN);
    f32x4 xv[4], acc[4];
    #pragma unroll
    for (int c = 0; c < 4; ++c) { xv[c] = __builtin_nontemporal_load(&x4[c*64+lane]); acc[c] = (f32x4)0.f; }
    int node = 0;
    #pragma unroll
    for (int d = 0; d < FFF_DEPTH; ++d) {
        const f32x4* w1 = reinterpret_cast<const f32x4*>(w1s + (size_t)node * N_IN);
        const f32x4* w2 = reinterpret_cast<const f32x4*>(w2s + (size_t)node * N_OUT);
        f32x4 w[4], v[4];
        #pragma unroll
        for (int c = 0; c < 4; ++c) { w[c] = w1[c*64+lane]; v[c] = w2[c*64+lane]; }
        float p0=0,p1=0,p2=0,p3=0;
        #pragma unroll
        for (int c = 0; c < 4; ++c) {
            p0 += xv[c][0]*w[c][0]; p1 += xv[c][1]*w[c][1];
            p2 += xv[c][2]*w[c][2]; p3 += xv[c][3]*w[c][3];
        }
        float lam = wave_sum((p0+p1)+(p2+p3));
        #pragma unroll
        for (int c = 0; c < 4; ++c) acc[c] += lam * v[c];
        node = node * 2 + 1 + (lam > 0.f ? 1 : 0);
    }
    f32x4* y4 = reinterpret_cast<f32x4*>(y + (size_t)b * N_OUT);
    #pragma unroll
    for (int c = 0; c < 4; ++c) store_stream(acc[c], &y4[c*64+lane]);
}

extern "C" void kernel_launch(void* const* d_in, const int* in_sizes, int n_in,
                              void* d_out, int out_size, void* d_ws, size_t ws_size,
                              hipStream_t stream) {
    const float* x   = (const float*)d_in[0];
    const float* w1s = (const float*)d_in[1];
    const float* w2s = (const float*)d_in[2];
    float* y = (float*)d_out;
    const int B = in_sizes[0] / N_IN;   // 65536

    float* lams16 = (float*)d_ws;
    int*   bins   = (int*)(lams16 + (size_t)B * 16);
    int*   cnt    = bins + (size_t)N_LEAF * BIN_CAP;
    const size_t need = ((size_t)B * 16 + (size_t)N_LEAF * BIN_CAP + N_LEAF) * 4;

    if (ws_size < need) {   // fallback: monolithic proven path
        fff_mono_kernel<<<(B + 3) / 4, 256, 0, stream>>>(x, w1s, w2s, y, B);
        return;
    }

    zero_cnt_kernel<<<1, N_LEAF, 0, stream>>>(cnt);
    route_kernel<<<ROUTE_BLOCKS, ROUTE_THREADS, N_STAGE * N_IN * sizeof(float), stream>>>(
        x, w1s, lams16, bins, cnt, B);
    accum_kernel<<<BLOCKS_PER_LEAF * N_LEAF, 256, 0, stream>>>(w2s, lams16, bins, cnt, y);
}